// Round 11
// baseline (609.669 us; speedup 1.0000x reference)
//
#include <hip/hip_runtime.h>

#define BB 8
#define LQ 4096
#define LK 32768
#define DD 64
#define UU 8000
#define NU 45
#define TQ2 128
#define TUC 160
#define NCH (UU/TUC)   // 50 chunks
#define CHB (TUC*DD*2) // 20480 bytes per chunk per array
#define KT5 512
#define NT5 64

typedef short short8 __attribute__((ext_vector_type(8)));
typedef float floatx16 __attribute__((ext_vector_type(16)));

__device__ __forceinline__ float bf2f(unsigned short h){ return __uint_as_float(((unsigned int)h) << 16); }
__device__ __forceinline__ unsigned short f2bf(float f){
  unsigned int u = __float_as_uint(f);
  u += 0x7FFFu + ((u >> 16) & 1u);
  return (unsigned short)(u >> 16);
}
__device__ __forceinline__ unsigned int fkey(float v){
  unsigned int u = __float_as_uint(v);
  return (u & 0x80000000u) ? ~u : (u | 0x80000000u);
}

// ---------------- prep: gather K_samp rows, Dekker-split f32 -> bf16 hi+mid ---------------------
// PRE-SWIZZLED global layout — 16B slot index oct is XOR'd with (row&7), so k_Mm can stage
// with a plain linear copy (global_load_lds) and read with swizzled ds_read offsets.
__global__ __launch_bounds__(256) void k_gather(const float* __restrict__ Kg, const int* __restrict__ idx,
                                                unsigned short* __restrict__ khi, unsigned short* __restrict__ kmid){
  const int b = blockIdx.y;
  const int row = blockIdx.x*32 + (threadIdx.x >> 3);
  const int oct = threadIdx.x & 7;
  const float* src = Kg + ((size_t)(b*LK + idx[row]))*DD + oct*8;
  float x[8];
  #pragma unroll
  for (int j=0;j<8;j++) x[j] = src[j];
  unsigned short h[8], m[8];
  #pragma unroll
  for (int j=0;j<8;j++){
    h[j] = f2bf(x[j]);
    m[j] = f2bf(x[j] - bf2f(h[j]));
  }
  const int osl = oct ^ (row & 7);                 // pre-swizzle the slot within the 8-row block
  size_t o = ((size_t)(b*UU + row))*DD + osl*8;
  #pragma unroll
  for (int j=0;j<8;j++){ khi[o+j]=h[j]; kmid[o+j]=m[j]; }
}

// partial sums of K_samp (for the exact mean term)
__global__ __launch_bounds__(64) void k_spart(const float* __restrict__ Kg, const int* __restrict__ idx,
                                              float* __restrict__ Spart){
  const int g = blockIdx.x, b = blockIdx.y, d = threadIdx.x;
  float acc = 0.0f;
  for (int j=0;j<64;j++){
    int u = g*64 + j;
    acc += Kg[((size_t)(b*LK + idx[u]))*DD + d];
  }
  Spart[((size_t)(b*125 + g))*DD + d] = acc;
}
__global__ __launch_bounds__(64) void k_sred(const float* __restrict__ Spart, float* __restrict__ Sb){
  const int b = blockIdx.x, d = threadIdx.x;
  float acc = 0.0f;
  for (int g=0; g<125; g++) acc += Spart[((size_t)(b*125 + g))*DD + d];
  Sb[b*DD + d] = acc;
}

// stage one 160-row chunk (khi+kmid, 40960 B) into LDS via global_load_lds.
// 8 waves x 5 units x 1024 B; waves 0-3 cover Bh, waves 4-7 cover Bm.
__device__ __forceinline__ void stage_chunk(const char* gh, const char* gm,
                                            unsigned short* Bhb, unsigned short* Bmb,
                                            int w, int lane){
  #pragma unroll
  for (int i=0;i<5;i++){
    const int u = w*5 + i;   // 0..39, wave-uniform
    if (u < 20){
      __builtin_amdgcn_global_load_lds(
        (const __attribute__((address_space(1))) void*)(gh + u*1024 + lane*16),
        (__attribute__((address_space(3))) void*)((char*)Bhb + u*1024 + lane*16),
        16, 0, 0);
    } else {
      __builtin_amdgcn_global_load_lds(
        (const __attribute__((address_space(1))) void*)(gm + (u-20)*1024 + lane*16),
        (__attribute__((address_space(3))) void*)((char*)Bmb + (u-20)*1024 + lane*16),
        16, 0, 0);
    }
  }
}

// ---------------- Stage 1 (MFMA): approx max + arg-chunk per q ----------------------------------
// v6: 2 qg x 4 sp wave layout — each wave holds A for 64 q rows (2 A-sets) and computes 24 MFMA
// per 8 B-fragment reads (was 12 per 8): LDS read traffic halves; MFMA pipe becomes binding.
// Tile base rotates by chunk so the 2-tile role is balanced long-run. XCD-affine b = wgid&7.
__global__ __launch_bounds__(512,2) void k_Mm(const float* __restrict__ q,
                                              const unsigned short* __restrict__ khi,
                                              const unsigned short* __restrict__ kmid,
                                              float* __restrict__ amaxG, int* __restrict__ acargG){
  const int wg = blockIdx.x;
  const int b = wg & 7, qt = wg >> 3;
  const int tid = threadIdx.x;
  const int w = tid >> 6, lane = tid & 63;
  const int qg = w & 1, sp = w >> 1;               // qg in [0,2), sp in [0,4)
  const int l31 = lane & 31, lh = lane >> 5;
  __shared__ __align__(16) unsigned short Bh[2][TUC*DD];
  __shared__ __align__(16) unsigned short Bm[2][TUC*DD];
  __shared__ float combV[TQ2][4];
  __shared__ int   combC[TQ2][4];

  short8 ahi[2][4], amid[2][4];
  #pragma unroll
  for (int a=0;a<2;a++){
    const int qrow = qt*TQ2 + qg*64 + a*32 + l31;
    const float* qp = q + ((size_t)(b*LQ) + qrow)*DD;
    #pragma unroll
    for (int s=0;s<4;s++){
      const int d0 = s*16 + lh*8;
      float4 x0 = *(const float4*)(qp + d0);
      float4 x1 = *(const float4*)(qp + d0 + 4);
      float xs[8] = {x0.x,x0.y,x0.z,x0.w,x1.x,x1.y,x1.z,x1.w};
      short8 h, m;
      #pragma unroll
      for (int j=0;j<8;j++){
        unsigned short hb = f2bf(xs[j]);
        unsigned short mb = f2bf(xs[j] - bf2f(hb));
        h[j] = (short)hb; m[j] = (short)mb;
      }
      ahi[a][s]=h; amid[a][s]=m;
    }
  }

  float vmax[2][16]; int carg[2][16];
  #pragma unroll
  for (int a=0;a<2;a++)
    #pragma unroll
    for (int r=0;r<16;r++){ vmax[a][r]=-INFINITY; carg[a][r]=0; }

  const size_t kbyte = (size_t)b*UU*DD*2;
  const char* ghbase = (const char*)khi + kbyte;
  const char* gmbase = (const char*)kmid + kbyte;

  // prologue: issue chunk 0 into buffer 0
  stage_chunk(ghbase, gmbase, &Bh[0][0], &Bm[0][0], w, lane);
  int cur = 0;

  for (int c=0;c<NCH;c++){
    __syncthreads();   // implicit vmcnt(0) drain: buf[cur] ready; all waves done with buf[cur^1]
    if (c+1 < NCH){
      stage_chunk(ghbase + (size_t)(c+1)*CHB, gmbase + (size_t)(c+1)*CHB,
                  &Bh[cur^1][0], &Bm[cur^1][0], w, lane);
    }
    const int tb = (sp + c) & 3;                   // rotating tile base (wave-uniform)
    #pragma unroll
    for (int k=0;k<2;k++){
      const int t = tb + k*4;
      if (t < 5){                                  // wave-uniform branch
        floatx16 acc0 = {0.f,0.f,0.f,0.f,0.f,0.f,0.f,0.f,0.f,0.f,0.f,0.f,0.f,0.f,0.f,0.f};
        floatx16 acc1 = {0.f,0.f,0.f,0.f,0.f,0.f,0.f,0.f,0.f,0.f,0.f,0.f,0.f,0.f,0.f,0.f};
        #pragma unroll
        for (int s=0;s<4;s++){
          // swizzled read: slot' = (s*2+lh) ^ (row&7), row&7 == l31&7
          const int eo = (t*32 + l31)*DD + (((s*2 + lh) ^ (l31 & 7))*8);
          short8 bh = *(const short8*)(&Bh[cur][eo]);
          short8 bm = *(const short8*)(&Bm[cur][eo]);
          acc0 = __builtin_amdgcn_mfma_f32_32x32x16_bf16(amid[0][s], bh, acc0, 0, 0, 0);
          acc0 = __builtin_amdgcn_mfma_f32_32x32x16_bf16(ahi[0][s],  bm, acc0, 0, 0, 0);
          acc0 = __builtin_amdgcn_mfma_f32_32x32x16_bf16(ahi[0][s],  bh, acc0, 0, 0, 0);
          acc1 = __builtin_amdgcn_mfma_f32_32x32x16_bf16(amid[1][s], bh, acc1, 0, 0, 0);
          acc1 = __builtin_amdgcn_mfma_f32_32x32x16_bf16(ahi[1][s],  bm, acc1, 0, 0, 0);
          acc1 = __builtin_amdgcn_mfma_f32_32x32x16_bf16(ahi[1][s],  bh, acc1, 0, 0, 0);
        }
        #pragma unroll
        for (int r=0;r<16;r++){
          if (acc0[r] > vmax[0][r]){ vmax[0][r] = acc0[r]; carg[0][r] = c; }
          if (acc1[r] > vmax[1][r]){ vmax[1][r] = acc1[r]; carg[1][r] = c; }
        }
      }
    }
    cur ^= 1;
  }
  #pragma unroll
  for (int st=1; st<32; st<<=1){
    #pragma unroll
    for (int a=0;a<2;a++)
      #pragma unroll
      for (int r=0;r<16;r++){
        float ov = __shfl_xor(vmax[a][r], st);
        int   oc = __shfl_xor(carg[a][r], st);
        if (ov > vmax[a][r]){ vmax[a][r]=ov; carg[a][r]=oc; }
      }
  }
  if (l31 == 0){
    #pragma unroll
    for (int a=0;a<2;a++)
      #pragma unroll
      for (int r=0;r<16;r++){
        int m = (r&3) + 8*(r>>2) + 4*lh;
        int ql = qg*64 + a*32 + m;
        combV[ql][sp] = vmax[a][r];
        combC[ql][sp] = carg[a][r];
      }
  }
  __syncthreads();
  if (tid < TQ2){
    float bv = combV[tid][0]; int bc = combC[tid][0];
    #pragma unroll
    for (int s=1;s<4;s++){
      float v = combV[tid][s];
      if (v > bv){ bv = v; bc = combC[tid][s]; }
    }
    amaxG[(size_t)b*LQ + qt*TQ2 + tid] = bv;
    acargG[(size_t)b*LQ + qt*TQ2 + tid] = bc;
  }
}

// ---------------- bucket q rows by their argmax chunk (hardened: clamped indices) ---------------
__global__ __launch_bounds__(256) void k_bucket(const int* __restrict__ acargG,
                                                int* __restrict__ qlist, int* __restrict__ bstart){
  const int b = blockIdx.x, tid = threadIdx.x;
  __shared__ int cnt[NCH];
  __shared__ int pos[NCH];
  if (tid < NCH) cnt[tid] = 0;
  __syncthreads();
  for (int qq = tid; qq < LQ; qq += 256){
    int ch = acargG[(size_t)b*LQ + qq];
    ch = (ch < 0) ? 0 : ((ch >= NCH) ? NCH-1 : ch);
    atomicAdd(&cnt[ch], 1);
  }
  __syncthreads();
  if (tid == 0){
    int acc = 0;
    for (int c=0;c<NCH;c++){ pos[c] = acc; bstart[b*64 + c] = acc; acc += cnt[c]; }
    bstart[b*64 + NCH] = acc;   // == LQ
  }
  __syncthreads();
  for (int qq = tid; qq < LQ; qq += 256){
    int ch = acargG[(size_t)b*LQ + qq];
    ch = (ch < 0) ? 0 : ((ch >= NCH) ? NCH-1 : ch);
    int p = atomicAdd(&pos[ch], 1);
    p = (p < 0) ? 0 : ((p >= LQ) ? LQ-1 : p);
    qlist[(size_t)b*LQ + p] = qq;
  }
}

// ---------------- refinement v5: 2 blocks per (chunk,b) + XCD affinity --------------------------
// Linear grid NCH*2*8; b = wgid&7 (XCD-affine), each block stages the chunk in LDS and processes
// half the bucket. 3 blocks/CU co-resident -> latency hiding. Same arithmetic, bitwise-same M.
__global__ __launch_bounds__(256,3) void k_refb(const float* __restrict__ q, const float* __restrict__ Kg,
                                                const int* __restrict__ idx, const float* __restrict__ Sb,
                                                const int* __restrict__ qlist, const int* __restrict__ bstart,
                                                float* __restrict__ M){
  const int wg = blockIdx.x;
  const int b = wg & 7;
  const int r0 = wg >> 3;
  const int ch = r0 >> 1, half = r0 & 1;
  const int tid = threadIdx.x;
  const int w = tid >> 6, lane = tid & 63;
  const int quad = lane & 3, rg = lane >> 2;
  __shared__ __align__(16) float Kl[TUC*DD];   // 40 KB
  float4* Kl4 = (float4*)Kl;
  for (int g = tid; g < TUC*16; g += 256){
    int row = g >> 4, s = g & 15;
    int gidx = idx[ch*TUC + row];
    float4 v = *(const float4*)(Kg + ((size_t)(b*LK + gidx))*DD + s*4);
    Kl4[row*16 + (s ^ (row & 7))] = v;
  }
  __syncthreads();

  const float4* sp4 = (const float4*)(Sb + b*DD + quad*16);
  const float4 S0 = sp4[0], S1 = sp4[1], S2 = sp4[2], S3 = sp4[3];
  const int sl0 = ((quad<<2)|0) ^ (rg & 7);
  const int sl1 = ((quad<<2)|1) ^ (rg & 7);
  const int sl2 = ((quad<<2)|2) ^ (rg & 7);
  const int sl3 = ((quad<<2)|3) ^ (rg & 7);
  const int rbs = rg*16;
  const int s0 = bstart[b*64 + ch], s1 = bstart[b*64 + ch + 1];
  const int gw = half*4 + w;                       // 0..7 across the two blocks of this bucket

  for (int i = s0 + (gw<<1); i < s1; i += 16){
    const int qa = qlist[(size_t)b*LQ + i];
    const int i2 = (i+1 < s1) ? i+1 : i;
    const int qb = qlist[(size_t)b*LQ + i2];
    const float4* ap = (const float4*)(q + ((size_t)(b*LQ + qa))*DD + quad*16);
    const float4* bp = (const float4*)(q + ((size_t)(b*LQ + qb))*DD + quad*16);
    const float4 A0 = ap[0], A1 = ap[1], A2 = ap[2], A3 = ap[3];
    const float4 B0 = bp[0], B1 = bp[1], B2 = bp[2], B3 = bp[3];
    float mxa = -INFINITY, mxb = -INFINITY;
    #pragma unroll
    for (int p=0;p<10;p++){
      const int base = p*256 + rbs;
      float4 k0 = Kl4[base + sl0];
      float4 k1 = Kl4[base + sl1];
      float4 k2 = Kl4[base + sl2];
      float4 k3 = Kl4[base + sl3];
      float a0 = A0.x*k0.x, a1 = A0.y*k0.y, a2 = A0.z*k0.z, a3 = A0.w*k0.w;
      a0 = fmaf(A1.x,k1.x,a0); a1 = fmaf(A1.y,k1.y,a1); a2 = fmaf(A1.z,k1.z,a2); a3 = fmaf(A1.w,k1.w,a3);
      a0 = fmaf(A2.x,k2.x,a0); a1 = fmaf(A2.y,k2.y,a1); a2 = fmaf(A2.z,k2.z,a2); a3 = fmaf(A2.w,k2.w,a3);
      a0 = fmaf(A3.x,k3.x,a0); a1 = fmaf(A3.y,k3.y,a1); a2 = fmaf(A3.z,k3.z,a2); a3 = fmaf(A3.w,k3.w,a3);
      float c0 = B0.x*k0.x, c1 = B0.y*k0.y, c2 = B0.z*k0.z, c3 = B0.w*k0.w;
      c0 = fmaf(B1.x,k1.x,c0); c1 = fmaf(B1.y,k1.y,c1); c2 = fmaf(B1.z,k1.z,c2); c3 = fmaf(B1.w,k1.w,c3);
      c0 = fmaf(B2.x,k2.x,c0); c1 = fmaf(B2.y,k2.y,c1); c2 = fmaf(B2.z,k2.z,c2); c3 = fmaf(B2.w,k2.w,c3);
      c0 = fmaf(B3.x,k3.x,c0); c1 = fmaf(B3.y,k3.y,c1); c2 = fmaf(B3.z,k3.z,c2); c3 = fmaf(B3.w,k3.w,c3);
      float sa = (a0+a1)+(a2+a3);
      float sc = (c0+c1)+(c2+c3);
      sa += __shfl_xor(sa, 1);
      sa += __shfl_xor(sa, 2);
      sc += __shfl_xor(sc, 1);
      sc += __shfl_xor(sc, 2);
      mxa = fmaxf(mxa, sa);
      mxb = fmaxf(mxb, sc);
    }
    #pragma unroll
    for (int st=4; st<64; st<<=1){
      mxa = fmaxf(mxa, __shfl_xor(mxa, st));
      mxb = fmaxf(mxb, __shfl_xor(mxb, st));
    }
    // exact mean terms
    float m0 = A0.x*S0.x, m1 = A0.y*S0.y, m2 = A0.z*S0.z, m3 = A0.w*S0.w;
    m0 = fmaf(A1.x,S1.x,m0); m1 = fmaf(A1.y,S1.y,m1); m2 = fmaf(A1.z,S1.z,m2); m3 = fmaf(A1.w,S1.w,m3);
    m0 = fmaf(A2.x,S2.x,m0); m1 = fmaf(A2.y,S2.y,m1); m2 = fmaf(A2.z,S2.z,m2); m3 = fmaf(A2.w,S2.w,m3);
    m0 = fmaf(A3.x,S3.x,m0); m1 = fmaf(A3.y,S3.y,m1); m2 = fmaf(A3.z,S3.z,m2); m3 = fmaf(A3.w,S3.w,m3);
    float msa = (m0+m1)+(m2+m3);
    msa += __shfl_xor(msa, 1);
    msa += __shfl_xor(msa, 2);
    float n0 = B0.x*S0.x, n1 = B0.y*S0.y, n2 = B0.z*S0.z, n3 = B0.w*S0.w;
    n0 = fmaf(B1.x,S1.x,n0); n1 = fmaf(B1.y,S1.y,n1); n2 = fmaf(B1.z,S1.z,n2); n3 = fmaf(B1.w,S1.w,n3);
    n0 = fmaf(B2.x,S2.x,n0); n1 = fmaf(B2.y,S2.y,n1); n2 = fmaf(B2.z,S2.z,n2); n3 = fmaf(B2.w,S2.w,n3);
    n0 = fmaf(B3.x,S3.x,n0); n1 = fmaf(B3.y,S3.y,n1); n2 = fmaf(B3.z,S3.z,n2); n3 = fmaf(B3.w,S3.w,n3);
    float msb = (n0+n1)+(n2+n3);
    msb += __shfl_xor(msb, 1);
    msb += __shfl_xor(msb, 2);
    if (lane == 0){
      M[(size_t)b*LQ + qa] = mxa - msa * (1.0f/8000.0f);
      if (i2 != i) M[(size_t)b*LQ + qb] = mxb - msb * (1.0f/8000.0f);
    }
  }
}

// ---------------- Stage 2: per-batch stable bottom-45 of M (cached local-min argmin) ------------
__global__ __launch_bounds__(256) void k_select(const float* __restrict__ Mg,
                                                const float* __restrict__ q,
                                                int* __restrict__ MtopG, float* __restrict__ Qred){
  const int b = blockIdx.x, tid = threadIdx.x;
  __shared__ float Mv[LQ];
  __shared__ unsigned long long wmin[4];
  __shared__ int mtop[NU];
  __shared__ int selB;
  for (int qq = tid; qq < LQ; qq += 256) Mv[qq] = Mg[(size_t)b*LQ + qq];
  __syncthreads();
  unsigned long long lm = ~0ull;
  #pragma unroll
  for (int i=0;i<16;i++){
    int qq = tid + 256*i;
    unsigned long long kk = (((unsigned long long)fkey(Mv[qq]))<<32) | (unsigned int)qq;
    lm = (kk < lm) ? kk : lm;
  }
  for (int i=0;i<NU;i++){
    unsigned long long v = lm;
    #pragma unroll
    for (int st=1; st<64; st<<=1){
      unsigned long long o = __shfl_xor(v, st);
      v = (o < v) ? o : v;
    }
    if ((tid & 63) == 0) wmin[tid>>6] = v;
    __syncthreads();
    if (tid == 0){
      unsigned long long g01 = (wmin[0] < wmin[1]) ? wmin[0] : wmin[1];
      unsigned long long g23 = (wmin[2] < wmin[3]) ? wmin[2] : wmin[3];
      unsigned long long g = (g01 < g23) ? g01 : g23;
      int sel = (int)(g & 0xFFFFFFFFull);
      mtop[i] = sel; selB = sel; Mv[sel] = INFINITY;
    }
    __syncthreads();
    int sel = selB;
    if (tid == (sel & 255)){
      unsigned long long nl = ~0ull;
      #pragma unroll
      for (int j=0;j<16;j++){
        int qq = tid + 256*j;
        unsigned long long kk = (((unsigned long long)fkey(Mv[qq]))<<32) | (unsigned int)qq;
        nl = (kk < nl) ? kk : nl;
      }
      lm = nl;
    }
    __syncthreads();
  }
  if (tid < NU) MtopG[b*NU + tid] = mtop[tid];
  for (int e = tid; e < NU*DD; e += 256){
    int ui = e >> 6, d = e & 63;
    Qred[((size_t)(b*NU + ui))*DD + d] = q[((size_t)(b*LQ + mtop[ui]))*DD + d];
  }
}

// ---------------- Stage 3: attn_scores (pre-softmax) -> output 1 --------------------------------
// NO local arrays (round-4 scratch lesson). K row in 16 NAMED float4 registers.
#define QFMA(i) { float4 p = qr4[i]; \
  a0 = fmaf(kv##i.x, p.x, a0); a1 = fmaf(kv##i.y, p.y, a1); \
  a2 = fmaf(kv##i.z, p.z, a2); a3 = fmaf(kv##i.w, p.w, a3); }

__global__ __launch_bounds__(256) void k_scores(const float* __restrict__ Kg,
                                                const float* __restrict__ Qred,
                                                float* __restrict__ out1){
  const int b = blockIdx.y;
  const int k = blockIdx.x*256 + threadIdx.x;
  const float4* kp4 = (const float4*)(Kg + ((size_t)(b*LK + k))*DD);
  const float4 kv0  = kp4[0],  kv1  = kp4[1],  kv2  = kp4[2],  kv3  = kp4[3];
  const float4 kv4  = kp4[4],  kv5  = kp4[5],  kv6  = kp4[6],  kv7  = kp4[7];
  const float4 kv8  = kp4[8],  kv9  = kp4[9],  kv10 = kp4[10], kv11 = kp4[11];
  const float4 kv12 = kp4[12], kv13 = kp4[13], kv14 = kp4[14], kv15 = kp4[15];
  for (int u=0; u<NU; u++){
    const float4* qr4 = (const float4*)(Qred + ((size_t)(b*NU+u))*DD);
    float a0 = 0.f, a1 = 0.f, a2 = 0.f, a3 = 0.f;
    QFMA(0)  QFMA(1)  QFMA(2)  QFMA(3)
    QFMA(4)  QFMA(5)  QFMA(6)  QFMA(7)
    QFMA(8)  QFMA(9)  QFMA(10) QFMA(11)
    QFMA(12) QFMA(13) QFMA(14) QFMA(15)
    float s = ((a0+a1)+(a2+a3)) * 0.125f;
    out1[((size_t)(b*NU+u)<<15) + k] = s;
  }
}

// ---------------- Stage 4a: softmax row stats ---------------------------------------------------
__global__ __launch_bounds__(256) void k_rowstats(const float* __restrict__ out1,
                                                  float* __restrict__ rowm, float* __restrict__ rowinvl){
  const int r = blockIdx.x, tid = threadIdx.x;
  const float* row = out1 + ((size_t)r << 15);
  __shared__ float red[256];
  float mx = -INFINITY;
  for (int k = tid; k < LK; k += 256) mx = fmaxf(mx, row[k]);
  red[tid] = mx; __syncthreads();
  for (int s=128;s>0;s>>=1){ if (tid<s) red[tid] = fmaxf(red[tid], red[tid+s]); __syncthreads(); }
  float m = red[0]; __syncthreads();
  float sm = 0.0f;
  for (int k = tid; k < LK; k += 256) sm += __expf(row[k] - m);
  red[tid] = sm; __syncthreads();
  for (int s=128;s>0;s>>=1){ if (tid<s) red[tid] += red[tid+s]; __syncthreads(); }
  if (tid==0){ rowm[r] = m; rowinvl[r] = 1.0f/red[0]; }
}

// ---------------- Stage 4b: PV partials per k-tile ----------------------------------------------
// 512 threads (8 waves x 6 u), KT5=512/NT5=64 -> 2 blocks/CU, 4 waves/SIMD.
__global__ __launch_bounds__(512) void k_pv(const float* __restrict__ Vg,
                                            const float* __restrict__ out1,
                                            const float* __restrict__ rowm, const float* __restrict__ rowinvl,
                                            float* __restrict__ pvpart){
  const int kt = blockIdx.x, b = blockIdx.y, tid = threadIdx.x;
  const int lane = tid & 63, w = tid >> 6;
  const int u0 = w*6;
  __shared__ float Vl[128][65];
  __shared__ __align__(16) float Pl[48][132];
  float acc[6];
  #pragma unroll
  for (int j=0;j<6;j++) acc[j] = 0.0f;
  for (int sc=0; sc<4; sc++){
    const int k0 = kt*KT5 + sc*128;
    {
      int r = tid >> 2, h = tid & 3;
      const float* vp = Vg + ((size_t)(b*LK + k0 + r))*DD + h*16;
      #pragma unroll
      for (int j=0;j<4;j++){
        float4 t = ((const float4*)vp)[j];
        Vl[r][h*16 + 4*j]   = t.x;
        Vl[r][h*16 + 4*j+1] = t.y;
        Vl[r][h*16 + 4*j+2] = t.z;
        Vl[r][h*16 + 4*j+3] = t.w;
      }
    }
    for (int e = tid; e < 48*128; e += 512){
      int u = e >> 7, kk = e & 127;
      float p = 0.0f;
      if (u < NU){
        int r = b*NU + u;
        float s = out1[((size_t)r<<15) + k0 + kk];
        p = __expf(s - rowm[r]) * rowinvl[r];
      }
      Pl[u][kk] = p;
    }
    __syncthreads();
    for (int kk4=0; kk4<32; kk4++){
      float v0 = Vl[4*kk4+0][lane];
      float v1 = Vl[4*kk4+1][lane];
      float v2 = Vl[4*kk4+2][lane];
      float v3 = Vl[4*kk4+3][lane];
      #pragma unroll
      for (int j=0;j<6;j++){
        float4 p = *reinterpret_cast<const float4*>(&Pl[u0+j][4*kk4]);
        acc[j] = fmaf(p.w, v3, fmaf(p.z, v2, fmaf(p.y, v1, fmaf(p.x, v0, acc[j]))));
      }
    }
    __syncthreads();
  }
  #pragma unroll
  for (int j=0;j<6;j++){
    if (u0 + j < NU){
      pvpart[(((size_t)(b*NU + u0 + j))*NT5 + kt)*DD + lane] = acc[j];
    }
  }
}

// ---------------- Stage 5: reduce PV partials -> output 0 ---------------------------------------
__global__ __launch_bounds__(256) void k_final(const float* __restrict__ pvpart, float* __restrict__ out0){
  int e = blockIdx.x*256 + threadIdx.x;
  if (e >= BB*NU*DD) return;
  int d = e & 63; int r = e >> 6;
  float s = 0.0f;
  for (int t=0;t<NT5;t++) s += pvpart[((size_t)r*NT5 + t)*DD + d];
  out0[e] = s;
}

extern "C" void kernel_launch(void* const* d_in, const int* in_sizes, int n_in,
                              void* d_out, int out_size, void* d_ws, size_t ws_size,
                              hipStream_t stream){
  const float* q  = (const float*)d_in[0];
  const float* K  = (const float*)d_in[1];
  const float* V  = (const float*)d_in[2];
  const int* idx  = (const int*)d_in[3];
  float* out0 = (float*)d_out;
  float* out1 = out0 + BB*NU*DD;

  float* ws = (float*)d_ws;
  unsigned short* khi  = (unsigned short*)ws;                        // 8*8000*64 bf16 = 8.192 MB
  float*  pvpart = ws;                                               // 5.90 MB (aliases khi; khi dead by k_pv)
  unsigned short* kmid = (unsigned short*)(ws + (size_t)BB*UU*DD/2); // 8.192 MB
  float* Spart   = ws + (size_t)BB*UU*DD;                            // 8*125*64 = 64000
  float* Sb      = Spart + 64000;                                    // 512
  float* amax    = Sb + 512;                                         // 32768
  int*   acarg   = (int*)(amax + BB*LQ);                             // 32768
  float* Mbq     = (float*)(acarg + BB*LQ);                          // 32768
  float* Qred    = Mbq + BB*LQ;                                      // 23040
  float* rowm    = Qred + (size_t)BB*NU*DD;                          // 512
  float* rowinvl = rowm + 512;                                       // 512
  int*   Mtop    = (int*)(rowinvl + 512);                            // 360
  int*   qlist   = Mtop + 512;                                       // 32768
  int*   bstart  = qlist + (size_t)BB*LQ;                            // 512

  k_gather<<<dim3(UU/32, BB), 256, 0, stream>>>(K, idx, khi, kmid);
  k_spart<<<dim3(125, BB), 64, 0, stream>>>(K, idx, Spart);
  k_sred<<<BB, 64, 0, stream>>>(Spart, Sb);
  k_Mm<<<(LQ/TQ2)*BB, 512, 0, stream>>>(q, khi, kmid, amax, acarg);
  k_bucket<<<BB, 256, 0, stream>>>(acarg, qlist, bstart);
  k_refb<<<NCH*2*BB, 256, 0, stream>>>(q, K, idx, Sb, qlist, bstart, Mbq);
  k_select<<<BB, 256, 0, stream>>>(Mbq, q, Mtop, Qred);
  k_scores<<<dim3(LK/256, BB), 256, 0, stream>>>(K, Qred, out1);
  k_rowstats<<<BB*NU, 256, 0, stream>>>(out1, rowm, rowinvl);
  k_pv<<<dim3(NT5, BB), 512, 0, stream>>>(V, out1, rowm, rowinvl, pvpart);
  k_final<<<(BB*NU*DD + 255)/256, 256, 0, stream>>>(pvpart, out0);
}

// Round 12
// 523.456 us; speedup vs baseline: 1.1647x; 1.1647x over previous
//
#include <hip/hip_runtime.h>

#define BB 8
#define LQ 4096
#define LK 32768
#define DD 64
#define UU 8000
#define NU 45
#define TQ2 128
#define TUC 160
#define NCH (UU/TUC)   // 50 chunks
#define CHB (TUC*DD*2) // 20480 bytes per chunk per array
#define KT5 512
#define NT5 64

typedef short short8 __attribute__((ext_vector_type(8)));
typedef float floatx16 __attribute__((ext_vector_type(16)));

__device__ __forceinline__ float bf2f(unsigned short h){ return __uint_as_float(((unsigned int)h) << 16); }
__device__ __forceinline__ unsigned short f2bf(float f){
  unsigned int u = __float_as_uint(f);
  u += 0x7FFFu + ((u >> 16) & 1u);
  return (unsigned short)(u >> 16);
}
__device__ __forceinline__ unsigned int fkey(float v){
  unsigned int u = __float_as_uint(v);
  return (u & 0x80000000u) ? ~u : (u | 0x80000000u);
}

// ---------------- prep: gather K_samp rows, Dekker-split f32 -> bf16 hi+mid ---------------------
__global__ __launch_bounds__(256) void k_gather(const float* __restrict__ Kg, const int* __restrict__ idx,
                                                unsigned short* __restrict__ khi, unsigned short* __restrict__ kmid){
  const int b = blockIdx.y;
  const int row = blockIdx.x*32 + (threadIdx.x >> 3);
  const int oct = threadIdx.x & 7;
  const float* src = Kg + ((size_t)(b*LK + idx[row]))*DD + oct*8;
  float x[8];
  #pragma unroll
  for (int j=0;j<8;j++) x[j] = src[j];
  unsigned short h[8], m[8];
  #pragma unroll
  for (int j=0;j<8;j++){
    h[j] = f2bf(x[j]);
    m[j] = f2bf(x[j] - bf2f(h[j]));
  }
  const int osl = oct ^ (row & 7);                 // pre-swizzle the slot within the 8-row block
  size_t o = ((size_t)(b*UU + row))*DD + osl*8;
  #pragma unroll
  for (int j=0;j<8;j++){ khi[o+j]=h[j]; kmid[o+j]=m[j]; }
}

// partial sums of K_samp (for the exact mean term)
__global__ __launch_bounds__(64) void k_spart(const float* __restrict__ Kg, const int* __restrict__ idx,
                                              float* __restrict__ Spart){
  const int g = blockIdx.x, b = blockIdx.y, d = threadIdx.x;
  float acc = 0.0f;
  for (int j=0;j<64;j++){
    int u = g*64 + j;
    acc += Kg[((size_t)(b*LK + idx[u]))*DD + d];
  }
  Spart[((size_t)(b*125 + g))*DD + d] = acc;
}
__global__ __launch_bounds__(64) void k_sred(const float* __restrict__ Spart, float* __restrict__ Sb){
  const int b = blockIdx.x, d = threadIdx.x;
  float acc = 0.0f;
  for (int g=0; g<125; g++) acc += Spart[((size_t)(b*125 + g))*DD + d];
  Sb[b*DD + d] = acc;
}

// stage one 160-row chunk (khi+kmid, 40960 B) into LDS via global_load_lds.
__device__ __forceinline__ void stage_chunk(const char* gh, const char* gm,
                                            unsigned short* Bhb, unsigned short* Bmb,
                                            int w, int lane){
  #pragma unroll
  for (int i=0;i<5;i++){
    const int u = w*5 + i;   // 0..39, wave-uniform
    if (u < 20){
      __builtin_amdgcn_global_load_lds(
        (const __attribute__((address_space(1))) void*)(gh + u*1024 + lane*16),
        (__attribute__((address_space(3))) void*)((char*)Bhb + u*1024 + lane*16),
        16, 0, 0);
    } else {
      __builtin_amdgcn_global_load_lds(
        (const __attribute__((address_space(1))) void*)(gm + (u-20)*1024 + lane*16),
        (__attribute__((address_space(3))) void*)((char*)Bmb + (u-20)*1024 + lane*16),
        16, 0, 0);
    }
  }
}

// ---------------- Stage 1 (MFMA): approx max + arg-chunk per q ----------------------------------
// v5 (REVERTED from v6 — round-11 lesson: 4-way sp split has 2:1 tile imbalance on the chunk
// barrier; v5's parity-alternating 3/2 split is the balanced layout). XCD-affine b = wgid&7.
__global__ __launch_bounds__(512,2) void k_Mm(const float* __restrict__ q,
                                              const unsigned short* __restrict__ khi,
                                              const unsigned short* __restrict__ kmid,
                                              float* __restrict__ amaxG, int* __restrict__ acargG){
  const int wg = blockIdx.x;
  const int b = wg & 7, qt = wg >> 3;
  const int tid = threadIdx.x;
  const int w = tid >> 6, lane = tid & 63;
  const int tr = w & 3, sp = w >> 2;
  const int l31 = lane & 31, lh = lane >> 5;
  __shared__ __align__(16) unsigned short Bh[2][TUC*DD];
  __shared__ __align__(16) unsigned short Bm[2][TUC*DD];
  __shared__ float combV[TQ2][2];
  __shared__ int   combC[TQ2][2];

  const int qrow = qt*TQ2 + tr*32 + l31;
  short8 ahi[4], amid[4];
  {
    const float* qp = q + ((size_t)(b*LQ) + qrow)*DD;
    #pragma unroll
    for (int s=0;s<4;s++){
      const int d0 = s*16 + lh*8;
      float4 x0 = *(const float4*)(qp + d0);
      float4 x1 = *(const float4*)(qp + d0 + 4);
      float xs[8] = {x0.x,x0.y,x0.z,x0.w,x1.x,x1.y,x1.z,x1.w};
      short8 h, m;
      #pragma unroll
      for (int j=0;j<8;j++){
        unsigned short hb = f2bf(xs[j]);
        unsigned short mb = f2bf(xs[j] - bf2f(hb));
        h[j] = (short)hb; m[j] = (short)mb;
      }
      ahi[s]=h; amid[s]=m;
    }
  }

  float vmax[16]; int carg[16];
  #pragma unroll
  for (int r=0;r<16;r++){ vmax[r]=-INFINITY; carg[r]=0; }

  const size_t kbyte = (size_t)b*UU*DD*2;
  const char* ghbase = (const char*)khi + kbyte;
  const char* gmbase = (const char*)kmid + kbyte;

  // prologue: issue chunk 0 into buffer 0
  stage_chunk(ghbase, gmbase, &Bh[0][0], &Bm[0][0], w, lane);
  int cur = 0;

  for (int c=0;c<NCH;c++){
    __syncthreads();   // implicit vmcnt(0) drain: buf[cur] ready; all waves done with buf[cur^1]
    if (c+1 < NCH){
      stage_chunk(ghbase + (size_t)(c+1)*CHB, gmbase + (size_t)(c+1)*CHB,
                  &Bh[cur^1][0], &Bm[cur^1][0], w, lane);
    }
    float lmax[16];
    #pragma unroll
    for (int r=0;r<16;r++) lmax[r] = -INFINITY;
    for (int t = ((c ^ sp) & 1); t < 5; t += 2){
      floatx16 accA = {0.f,0.f,0.f,0.f,0.f,0.f,0.f,0.f,0.f,0.f,0.f,0.f,0.f,0.f,0.f,0.f};
      floatx16 accB = {0.f,0.f,0.f,0.f,0.f,0.f,0.f,0.f,0.f,0.f,0.f,0.f,0.f,0.f,0.f,0.f};
      #pragma unroll
      for (int s=0;s<4;s++){
        const int eo = (t*32 + l31)*DD + (((s*2 + lh) ^ (l31 & 7))*8);
        short8 bh = *(const short8*)(&Bh[cur][eo]);
        short8 bm = *(const short8*)(&Bm[cur][eo]);
        if (s & 1){
          accB = __builtin_amdgcn_mfma_f32_32x32x16_bf16(amid[s], bh, accB, 0, 0, 0);
          accB = __builtin_amdgcn_mfma_f32_32x32x16_bf16(ahi[s],  bm, accB, 0, 0, 0);
          accB = __builtin_amdgcn_mfma_f32_32x32x16_bf16(ahi[s],  bh, accB, 0, 0, 0);
        } else {
          accA = __builtin_amdgcn_mfma_f32_32x32x16_bf16(amid[s], bh, accA, 0, 0, 0);
          accA = __builtin_amdgcn_mfma_f32_32x32x16_bf16(ahi[s],  bm, accA, 0, 0, 0);
          accA = __builtin_amdgcn_mfma_f32_32x32x16_bf16(ahi[s],  bh, accA, 0, 0, 0);
        }
      }
      #pragma unroll
      for (int r=0;r<16;r++) lmax[r] = fmaxf(lmax[r], accA[r] + accB[r]);
    }
    #pragma unroll
    for (int r=0;r<16;r++){
      if (lmax[r] > vmax[r]){ vmax[r] = lmax[r]; carg[r] = c; }
    }
    cur ^= 1;
  }
  #pragma unroll
  for (int st=1; st<32; st<<=1){
    #pragma unroll
    for (int r=0;r<16;r++){
      float ov = __shfl_xor(vmax[r], st);
      int   oc = __shfl_xor(carg[r], st);
      if (ov > vmax[r]){ vmax[r]=ov; carg[r]=oc; }
    }
  }
  if (l31 == 0){
    #pragma unroll
    for (int r=0;r<16;r++){
      int m = (r&3) + 8*(r>>2) + 4*lh;
      int ql = tr*32 + m;
      combV[ql][sp] = vmax[r];
      combC[ql][sp] = carg[r];
    }
  }
  __syncthreads();
  if (tid < TQ2){
    float v0 = combV[tid][0], v1 = combV[tid][1];
    int   c0 = combC[tid][0], c1 = combC[tid][1];
    bool t1 = v1 > v0;
    amaxG[(size_t)b*LQ + qt*TQ2 + tid] = t1 ? v1 : v0;
    acargG[(size_t)b*LQ + qt*TQ2 + tid] = t1 ? c1 : c0;
  }
}

// ---------------- bucket q rows by their argmax chunk (hardened: clamped indices) ---------------
__global__ __launch_bounds__(256) void k_bucket(const int* __restrict__ acargG,
                                                int* __restrict__ qlist, int* __restrict__ bstart){
  const int b = blockIdx.x, tid = threadIdx.x;
  __shared__ int cnt[NCH];
  __shared__ int pos[NCH];
  if (tid < NCH) cnt[tid] = 0;
  __syncthreads();
  for (int qq = tid; qq < LQ; qq += 256){
    int ch = acargG[(size_t)b*LQ + qq];
    ch = (ch < 0) ? 0 : ((ch >= NCH) ? NCH-1 : ch);
    atomicAdd(&cnt[ch], 1);
  }
  __syncthreads();
  if (tid == 0){
    int acc = 0;
    for (int c=0;c<NCH;c++){ pos[c] = acc; bstart[b*64 + c] = acc; acc += cnt[c]; }
    bstart[b*64 + NCH] = acc;   // == LQ
  }
  __syncthreads();
  for (int qq = tid; qq < LQ; qq += 256){
    int ch = acargG[(size_t)b*LQ + qq];
    ch = (ch < 0) ? 0 : ((ch >= NCH) ? NCH-1 : ch);
    int p = atomicAdd(&pos[ch], 1);
    p = (p < 0) ? 0 : ((p >= LQ) ? LQ-1 : p);
    qlist[(size_t)b*LQ + p] = qq;
  }
}

// ---------------- refinement v6: 4 blocks per (chunk,b) + XCD affinity --------------------------
// Round-9 showed k_refb is ~90% latency-exposed at low occupancy; SPLIT 2->4 doubles resident
// parallelism. Each block stages the chunk in LDS (dup, L2-hot) and takes a quarter of the bucket.
__global__ __launch_bounds__(256,3) void k_refb(const float* __restrict__ q, const float* __restrict__ Kg,
                                                const int* __restrict__ idx, const float* __restrict__ Sb,
                                                const int* __restrict__ qlist, const int* __restrict__ bstart,
                                                float* __restrict__ M){
  const int wg = blockIdx.x;
  const int b = wg & 7;
  const int r0 = wg >> 3;
  const int ch = r0 >> 2, part = r0 & 3;
  const int tid = threadIdx.x;
  const int w = tid >> 6, lane = tid & 63;
  const int quad = lane & 3, rg = lane >> 2;
  __shared__ __align__(16) float Kl[TUC*DD];   // 40 KB
  float4* Kl4 = (float4*)Kl;
  for (int g = tid; g < TUC*16; g += 256){
    int row = g >> 4, s = g & 15;
    int gidx = idx[ch*TUC + row];
    float4 v = *(const float4*)(Kg + ((size_t)(b*LK + gidx))*DD + s*4);
    Kl4[row*16 + (s ^ (row & 7))] = v;
  }
  __syncthreads();

  const float4* sp4 = (const float4*)(Sb + b*DD + quad*16);
  const float4 S0 = sp4[0], S1 = sp4[1], S2 = sp4[2], S3 = sp4[3];
  const int sl0 = ((quad<<2)|0) ^ (rg & 7);
  const int sl1 = ((quad<<2)|1) ^ (rg & 7);
  const int sl2 = ((quad<<2)|2) ^ (rg & 7);
  const int sl3 = ((quad<<2)|3) ^ (rg & 7);
  const int rbs = rg*16;
  const int s0 = bstart[b*64 + ch], s1 = bstart[b*64 + ch + 1];
  const int gw = part*4 + w;                       // 0..15 across the four blocks of this bucket

  for (int i = s0 + (gw<<1); i < s1; i += 32){
    const int qa = qlist[(size_t)b*LQ + i];
    const int i2 = (i+1 < s1) ? i+1 : i;
    const int qb = qlist[(size_t)b*LQ + i2];
    const float4* ap = (const float4*)(q + ((size_t)(b*LQ + qa))*DD + quad*16);
    const float4* bp = (const float4*)(q + ((size_t)(b*LQ + qb))*DD + quad*16);
    const float4 A0 = ap[0], A1 = ap[1], A2 = ap[2], A3 = ap[3];
    const float4 B0 = bp[0], B1 = bp[1], B2 = bp[2], B3 = bp[3];
    float mxa = -INFINITY, mxb = -INFINITY;
    #pragma unroll
    for (int p=0;p<10;p++){
      const int base = p*256 + rbs;
      float4 k0 = Kl4[base + sl0];
      float4 k1 = Kl4[base + sl1];
      float4 k2 = Kl4[base + sl2];
      float4 k3 = Kl4[base + sl3];
      float a0 = A0.x*k0.x, a1 = A0.y*k0.y, a2 = A0.z*k0.z, a3 = A0.w*k0.w;
      a0 = fmaf(A1.x,k1.x,a0); a1 = fmaf(A1.y,k1.y,a1); a2 = fmaf(A1.z,k1.z,a2); a3 = fmaf(A1.w,k1.w,a3);
      a0 = fmaf(A2.x,k2.x,a0); a1 = fmaf(A2.y,k2.y,a1); a2 = fmaf(A2.z,k2.z,a2); a3 = fmaf(A2.w,k2.w,a3);
      a0 = fmaf(A3.x,k3.x,a0); a1 = fmaf(A3.y,k3.y,a1); a2 = fmaf(A3.z,k3.z,a2); a3 = fmaf(A3.w,k3.w,a3);
      float c0 = B0.x*k0.x, c1 = B0.y*k0.y, c2 = B0.z*k0.z, c3 = B0.w*k0.w;
      c0 = fmaf(B1.x,k1.x,c0); c1 = fmaf(B1.y,k1.y,c1); c2 = fmaf(B1.z,k1.z,c2); c3 = fmaf(B1.w,k1.w,c3);
      c0 = fmaf(B2.x,k2.x,c0); c1 = fmaf(B2.y,k2.y,c1); c2 = fmaf(B2.z,k2.z,c2); c3 = fmaf(B2.w,k2.w,c3);
      c0 = fmaf(B3.x,k3.x,c0); c1 = fmaf(B3.y,k3.y,c1); c2 = fmaf(B3.z,k3.z,c2); c3 = fmaf(B3.w,k3.w,c3);
      float sa = (a0+a1)+(a2+a3);
      float sc = (c0+c1)+(c2+c3);
      sa += __shfl_xor(sa, 1);
      sa += __shfl_xor(sa, 2);
      sc += __shfl_xor(sc, 1);
      sc += __shfl_xor(sc, 2);
      mxa = fmaxf(mxa, sa);
      mxb = fmaxf(mxb, sc);
    }
    #pragma unroll
    for (int st=4; st<64; st<<=1){
      mxa = fmaxf(mxa, __shfl_xor(mxa, st));
      mxb = fmaxf(mxb, __shfl_xor(mxb, st));
    }
    // exact mean terms
    float m0 = A0.x*S0.x, m1 = A0.y*S0.y, m2 = A0.z*S0.z, m3 = A0.w*S0.w;
    m0 = fmaf(A1.x,S1.x,m0); m1 = fmaf(A1.y,S1.y,m1); m2 = fmaf(A1.z,S1.z,m2); m3 = fmaf(A1.w,S1.w,m3);
    m0 = fmaf(A2.x,S2.x,m0); m1 = fmaf(A2.y,S2.y,m1); m2 = fmaf(A2.z,S2.z,m2); m3 = fmaf(A2.w,S2.w,m3);
    m0 = fmaf(A3.x,S3.x,m0); m1 = fmaf(A3.y,S3.y,m1); m2 = fmaf(A3.z,S3.z,m2); m3 = fmaf(A3.w,S3.w,m3);
    float msa = (m0+m1)+(m2+m3);
    msa += __shfl_xor(msa, 1);
    msa += __shfl_xor(msa, 2);
    float n0 = B0.x*S0.x, n1 = B0.y*S0.y, n2 = B0.z*S0.z, n3 = B0.w*S0.w;
    n0 = fmaf(B1.x,S1.x,n0); n1 = fmaf(B1.y,S1.y,n1); n2 = fmaf(B1.z,S1.z,n2); n3 = fmaf(B1.w,S1.w,n3);
    n0 = fmaf(B2.x,S2.x,n0); n1 = fmaf(B2.y,S2.y,n1); n2 = fmaf(B2.z,S2.z,n2); n3 = fmaf(B2.w,S2.w,n3);
    n0 = fmaf(B3.x,S3.x,n0); n1 = fmaf(B3.y,S3.y,n1); n2 = fmaf(B3.z,S3.z,n2); n3 = fmaf(B3.w,S3.w,n3);
    float msb = (n0+n1)+(n2+n3);
    msb += __shfl_xor(msb, 1);
    msb += __shfl_xor(msb, 2);
    if (lane == 0){
      M[(size_t)b*LQ + qa] = mxa - msa * (1.0f/8000.0f);
      if (i2 != i) M[(size_t)b*LQ + qb] = mxb - msb * (1.0f/8000.0f);
    }
  }
}

// ---------------- Stage 2: per-batch stable bottom-45 of M (cached local-min argmin) ------------
__global__ __launch_bounds__(256) void k_select(const float* __restrict__ Mg,
                                                const float* __restrict__ q,
                                                int* __restrict__ MtopG, float* __restrict__ Qred){
  const int b = blockIdx.x, tid = threadIdx.x;
  __shared__ float Mv[LQ];
  __shared__ unsigned long long wmin[4];
  __shared__ int mtop[NU];
  __shared__ int selB;
  for (int qq = tid; qq < LQ; qq += 256) Mv[qq] = Mg[(size_t)b*LQ + qq];
  __syncthreads();
  unsigned long long lm = ~0ull;
  #pragma unroll
  for (int i=0;i<16;i++){
    int qq = tid + 256*i;
    unsigned long long kk = (((unsigned long long)fkey(Mv[qq]))<<32) | (unsigned int)qq;
    lm = (kk < lm) ? kk : lm;
  }
  for (int i=0;i<NU;i++){
    unsigned long long v = lm;
    #pragma unroll
    for (int st=1; st<64; st<<=1){
      unsigned long long o = __shfl_xor(v, st);
      v = (o < v) ? o : v;
    }
    if ((tid & 63) == 0) wmin[tid>>6] = v;
    __syncthreads();
    if (tid == 0){
      unsigned long long g01 = (wmin[0] < wmin[1]) ? wmin[0] : wmin[1];
      unsigned long long g23 = (wmin[2] < wmin[3]) ? wmin[2] : wmin[3];
      unsigned long long g = (g01 < g23) ? g01 : g23;
      int sel = (int)(g & 0xFFFFFFFFull);
      mtop[i] = sel; selB = sel; Mv[sel] = INFINITY;
    }
    __syncthreads();
    int sel = selB;
    if (tid == (sel & 255)){
      unsigned long long nl = ~0ull;
      #pragma unroll
      for (int j=0;j<16;j++){
        int qq = tid + 256*j;
        unsigned long long kk = (((unsigned long long)fkey(Mv[qq]))<<32) | (unsigned int)qq;
        nl = (kk < nl) ? kk : nl;
      }
      lm = nl;
    }
    __syncthreads();
  }
  if (tid < NU) MtopG[b*NU + tid] = mtop[tid];
  for (int e = tid; e < NU*DD; e += 256){
    int ui = e >> 6, d = e & 63;
    Qred[((size_t)(b*NU + ui))*DD + d] = q[((size_t)(b*LQ + mtop[ui]))*DD + d];
  }
}

// ---------------- Stage 3: attn_scores + per-wave softmax partials ------------------------------
// v6: fused partial rowstats — per (row, wave-of-64-k): wave max m_w and wave sum of exp(s-m_w),
// stored to pm/pl[360][512]. Kills k_rowstats' 94 MB re-read of out1.
#define QFMA(i) { float4 p = qr4[i]; \
  a0 = fmaf(kv##i.x, p.x, a0); a1 = fmaf(kv##i.y, p.y, a1); \
  a2 = fmaf(kv##i.z, p.z, a2); a3 = fmaf(kv##i.w, p.w, a3); }

__global__ __launch_bounds__(256) void k_scores(const float* __restrict__ Kg,
                                                const float* __restrict__ Qred,
                                                float* __restrict__ out1,
                                                float* __restrict__ pm, float* __restrict__ pl){
  const int b = blockIdx.y;
  const int k = blockIdx.x*256 + threadIdx.x;
  const int lane = threadIdx.x & 63, w = threadIdx.x >> 6;
  const int pi = blockIdx.x*4 + w;                 // 0..511 partial slot
  const float4* kp4 = (const float4*)(Kg + ((size_t)(b*LK + k))*DD);
  const float4 kv0  = kp4[0],  kv1  = kp4[1],  kv2  = kp4[2],  kv3  = kp4[3];
  const float4 kv4  = kp4[4],  kv5  = kp4[5],  kv6  = kp4[6],  kv7  = kp4[7];
  const float4 kv8  = kp4[8],  kv9  = kp4[9],  kv10 = kp4[10], kv11 = kp4[11];
  const float4 kv12 = kp4[12], kv13 = kp4[13], kv14 = kp4[14], kv15 = kp4[15];
  for (int u=0; u<NU; u++){
    const float4* qr4 = (const float4*)(Qred + ((size_t)(b*NU+u))*DD);
    float a0 = 0.f, a1 = 0.f, a2 = 0.f, a3 = 0.f;
    QFMA(0)  QFMA(1)  QFMA(2)  QFMA(3)
    QFMA(4)  QFMA(5)  QFMA(6)  QFMA(7)
    QFMA(8)  QFMA(9)  QFMA(10) QFMA(11)
    QFMA(12) QFMA(13) QFMA(14) QFMA(15)
    float s = ((a0+a1)+(a2+a3)) * 0.125f;
    out1[((size_t)(b*NU+u)<<15) + k] = s;
    // wave-level softmax partials
    float mw = s;
    #pragma unroll
    for (int st=1; st<64; st<<=1) mw = fmaxf(mw, __shfl_xor(mw, st));
    float e = __expf(s - mw);
    #pragma unroll
    for (int st=1; st<64; st<<=1) e += __shfl_xor(e, st);
    if (lane == 0){
      size_t r = (size_t)(b*NU + u);
      pm[r*512 + pi] = mw;
      pl[r*512 + pi] = e;
    }
  }
}

// ---------------- Stage 4a: combine softmax partials (1.4 MB, replaces 94 MB pass) --------------
__global__ __launch_bounds__(256) void k_rowred(const float* __restrict__ pm, const float* __restrict__ pl,
                                                float* __restrict__ rowm, float* __restrict__ rowinvl){
  const int r = blockIdx.x, tid = threadIdx.x;
  __shared__ float red[256];
  float m = -INFINITY;
  for (int i = tid; i < 512; i += 256) m = fmaxf(m, pm[(size_t)r*512 + i]);
  red[tid] = m; __syncthreads();
  for (int s=128;s>0;s>>=1){ if (tid<s) red[tid] = fmaxf(red[tid], red[tid+s]); __syncthreads(); }
  m = red[0]; __syncthreads();
  float sm = 0.0f;
  for (int i = tid; i < 512; i += 256)
    sm += pl[(size_t)r*512 + i] * __expf(pm[(size_t)r*512 + i] - m);
  red[tid] = sm; __syncthreads();
  for (int s=128;s>0;s>>=1){ if (tid<s) red[tid] += red[tid+s]; __syncthreads(); }
  if (tid==0){ rowm[r] = m; rowinvl[r] = 1.0f/red[0]; }
}

// ---------------- Stage 4b: PV partials per k-tile ----------------------------------------------
// 512 threads (8 waves x 6 u), KT5=512/NT5=64 -> 2 blocks/CU, 4 waves/SIMD.
__global__ __launch_bounds__(512) void k_pv(const float* __restrict__ Vg,
                                            const float* __restrict__ out1,
                                            const float* __restrict__ rowm, const float* __restrict__ rowinvl,
                                            float* __restrict__ pvpart){
  const int kt = blockIdx.x, b = blockIdx.y, tid = threadIdx.x;
  const int lane = tid & 63, w = tid >> 6;
  const int u0 = w*6;
  __shared__ float Vl[128][65];
  __shared__ __align__(16) float Pl[48][132];
  float acc[6];
  #pragma unroll
  for (int j=0;j<6;j++) acc[j] = 0.0f;
  for (int sc=0; sc<4; sc++){
    const int k0 = kt*KT5 + sc*128;
    {
      int r = tid >> 2, h = tid & 3;
      const float* vp = Vg + ((size_t)(b*LK + k0 + r))*DD + h*16;
      #pragma unroll
      for (int j=0;j<4;j++){
        float4 t = ((const float4*)vp)[j];
        Vl[r][h*16 + 4*j]   = t.x;
        Vl[r][h*16 + 4*j+1] = t.y;
        Vl[r][h*16 + 4*j+2] = t.z;
        Vl[r][h*16 + 4*j+3] = t.w;
      }
    }
    for (int e = tid; e < 48*128; e += 512){
      int u = e >> 7, kk = e & 127;
      float p = 0.0f;
      if (u < NU){
        int r = b*NU + u;
        float s = out1[((size_t)r<<15) + k0 + kk];
        p = __expf(s - rowm[r]) * rowinvl[r];
      }
      Pl[u][kk] = p;
    }
    __syncthreads();
    for (int kk4=0; kk4<32; kk4++){
      float v0 = Vl[4*kk4+0][lane];
      float v1 = Vl[4*kk4+1][lane];
      float v2 = Vl[4*kk4+2][lane];
      float v3 = Vl[4*kk4+3][lane];
      #pragma unroll
      for (int j=0;j<6;j++){
        float4 p = *reinterpret_cast<const float4*>(&Pl[u0+j][4*kk4]);
        acc[j] = fmaf(p.w, v3, fmaf(p.z, v2, fmaf(p.y, v1, fmaf(p.x, v0, acc[j]))));
      }
    }
    __syncthreads();
  }
  #pragma unroll
  for (int j=0;j<6;j++){
    if (u0 + j < NU){
      pvpart[(((size_t)(b*NU + u0 + j))*NT5 + kt)*DD + lane] = acc[j];
    }
  }
}

// ---------------- Stage 5: reduce PV partials -> output 0 ---------------------------------------
__global__ __launch_bounds__(256) void k_final(const float* __restrict__ pvpart, float* __restrict__ out0){
  int e = blockIdx.x*256 + threadIdx.x;
  if (e >= BB*NU*DD) return;
  int d = e & 63; int r = e >> 6;
  float s = 0.0f;
  for (int t=0;t<NT5;t++) s += pvpart[((size_t)r*NT5 + t)*DD + d];
  out0[e] = s;
}

extern "C" void kernel_launch(void* const* d_in, const int* in_sizes, int n_in,
                              void* d_out, int out_size, void* d_ws, size_t ws_size,
                              hipStream_t stream){
  const float* q  = (const float*)d_in[0];
  const float* K  = (const float*)d_in[1];
  const float* V  = (const float*)d_in[2];
  const int* idx  = (const int*)d_in[3];
  float* out0 = (float*)d_out;
  float* out1 = out0 + BB*NU*DD;

  float* ws = (float*)d_ws;
  unsigned short* khi  = (unsigned short*)ws;                        // 8*8000*64 bf16 = 8.192 MB
  float*  pvpart = ws;                                               // 5.90 MB (aliases khi; khi dead by k_pv)
  unsigned short* kmid = (unsigned short*)(ws + (size_t)BB*UU*DD/2); // 8.192 MB
  float* pm      = ws + (size_t)BB*UU*DD/2;                          // 360*512 f32 (aliases kmid; kmid dead after k_Mm)
  float* pl      = pm + (size_t)BB*NU*512;                           // 360*512 f32
  float* Spart   = ws + (size_t)BB*UU*DD;                            // 8*125*64 = 64000
  float* Sb      = Spart + 64000;                                    // 512
  float* amax    = Sb + 512;                                         // 32768
  int*   acarg   = (int*)(amax + BB*LQ);                             // 32768
  float* Mbq     = (float*)(acarg + BB*LQ);                          // 32768
  float* Qred    = Mbq + BB*LQ;                                      // 23040
  float* rowm    = Qred + (size_t)BB*NU*DD;                          // 512
  float* rowinvl = rowm + 512;                                       // 512
  int*   Mtop    = (int*)(rowinvl + 512);                            // 360
  int*   qlist   = Mtop + 512;                                       // 32768
  int*   bstart  = qlist + (size_t)BB*LQ;                            // 512

  k_gather<<<dim3(UU/32, BB), 256, 0, stream>>>(K, idx, khi, kmid);
  k_spart<<<dim3(125, BB), 64, 0, stream>>>(K, idx, Spart);
  k_sred<<<BB, 64, 0, stream>>>(Spart, Sb);
  k_Mm<<<(LQ/TQ2)*BB, 512, 0, stream>>>(q, khi, kmid, amax, acarg);
  k_bucket<<<BB, 256, 0, stream>>>(acarg, qlist, bstart);
  k_refb<<<NCH*4*BB, 256, 0, stream>>>(q, K, idx, Sb, qlist, bstart, Mbq);
  k_select<<<BB, 256, 0, stream>>>(Mbq, q, Mtop, Qred);
  k_scores<<<dim3(LK/256, BB), 256, 0, stream>>>(K, Qred, out1, pm, pl);
  k_rowred<<<BB*NU, 256, 0, stream>>>(pm, pl, rowm, rowinvl);
  k_pv<<<dim3(NT5, BB), 512, 0, stream>>>(V, out1, rowm, rowinvl, pvpart);
  k_final<<<(BB*NU*DD + 255)/256, 256, 0, stream>>>(pvpart, out0);
}